// Round 3
// baseline (194.324 us; speedup 1.0000x reference)
//
#include <hip/hip_runtime.h>
#include <math.h>

#define BB 64
#define TT 2048
#define DD 256
#define SS 16
#define HH 2          // blocks per segment (load-balance split); R3: 4->2 halves
                      // grid (4096 blocks) and partials traffic (4 MiB)
#define CEPS 1e-8f

// ---------------- Kernel 1: per-segment partial means ----------------
// grid = BB*2*SS*HH = 4096 blocks, 256 threads. Each block sums a contiguous
// half of its segment's rows, pre-scaled by 1/seg_len, into partials.
// XCD swizzle: low 3 bits of blockIdx = b%8, so all 64 blocks of one batch
// land on one XCD consecutively -> pos/neg overlapping rows hit that XCD's L2.
// NOTE (R1 post-mortem): do NOT fuse the loss in via a completion gate —
// agent-scope fences flush the per-XCD L2 once per block and cost ~1 ms.
// A second dispatch costs ~2 us.
__global__ __launch_bounds__(256) void seg_mean_kernel(
        const float* __restrict__ feat,
        const int* __restrict__ idx_pos,
        const int* __restrict__ idx_neg,
        float* __restrict__ partials,  // [BB][2][SS][HH][DD]
        int* __restrict__ validf,      // [BB][2][SS]
        float* __restrict__ out) {
    // R3: zero the output here instead of a separate memset dispatch.
    // Visibility to the (later) loss_kernel dispatch is guaranteed by
    // in-stream kernel ordering (CP flushes caches between dispatches).
    if (blockIdx.x == 0 && threadIdx.x == 0) out[0] = 0.f;

    int blk   = blockIdx.x;
    int xcd   = blk & 7;
    int inner = blk >> 3;          // 0..511
    int work  = inner & 63;        // (set,s,h)
    int bg    = inner >> 6;        // 0..7
    int b     = bg * 8 + xcd;
    int set   = work >> 5;
    int s     = (work >> 1) & 15;
    int h     = work & 1;
    const int* row = (set == 0 ? idx_pos : idx_neg) + b * 32;

    // valid = cumprod(starts >= 0) up to and including s
    int v = 1;
    for (int j = 0; j <= s; ++j) v &= (row[2 * j] >= 0) ? 1 : 0;

    int start = row[2 * s];
    int end   = row[2 * s + 1];
    int seg_len = end - start;
    if (seg_len < 1) seg_len = 1;
    int t0 = start < 0 ? 0 : start;
    int t1 = start + seg_len;
    if (t1 > TT) t1 = TT;
    int len = t1 - t0;
    if (len < 0) len = 0;

    // this block's half of the row range
    int q0 = t0 + ((len * h) >> 1);
    int q1 = t0 + ((len * (h + 1)) >> 1);

    int tid = threadIdx.x;
    int d4  = tid & 63;
    int r   = tid >> 6;

    float4 a0 = make_float4(0.f, 0.f, 0.f, 0.f);
    float4 a1 = a0, a2 = a0, a3 = a0;
    if (v) {
        const float4* fp = (const float4*)(feat + (size_t)b * TT * DD);
        int t = q0 + r;
        for (; t + 12 < q1; t += 16) {
            float4 x0 = fp[(size_t)t * 64 + d4];
            float4 x1 = fp[(size_t)(t + 4) * 64 + d4];
            float4 x2 = fp[(size_t)(t + 8) * 64 + d4];
            float4 x3 = fp[(size_t)(t + 12) * 64 + d4];
            a0.x += x0.x; a0.y += x0.y; a0.z += x0.z; a0.w += x0.w;
            a1.x += x1.x; a1.y += x1.y; a1.z += x1.z; a1.w += x1.w;
            a2.x += x2.x; a2.y += x2.y; a2.z += x2.z; a2.w += x2.w;
            a3.x += x3.x; a3.y += x3.y; a3.z += x3.z; a3.w += x3.w;
        }
        for (; t < q1; t += 4) {
            float4 x = fp[(size_t)t * 64 + d4];
            a0.x += x.x; a0.y += x.y; a0.z += x.z; a0.w += x.w;
        }
    }
    float4 acc;
    acc.x = (a0.x + a1.x) + (a2.x + a3.x);
    acc.y = (a0.y + a1.y) + (a2.y + a3.y);
    acc.z = (a0.z + a1.z) + (a2.z + a3.z);
    acc.w = (a0.w + a1.w) + (a2.w + a3.w);

    __shared__ float4 red[256];
    red[tid] = acc;
    __syncthreads();
    if (r == 0) {
        float4 b0 = red[d4];
        float4 b1 = red[d4 + 64];
        float4 b2 = red[d4 + 128];
        float4 b3 = red[d4 + 192];
        float inv = 1.0f / (float)seg_len;
        float4 m;
        m.x = ((b0.x + b1.x) + (b2.x + b3.x)) * inv;
        m.y = ((b0.y + b1.y) + (b2.y + b3.y)) * inv;
        m.z = ((b0.z + b1.z) + (b2.z + b3.z)) * inv;
        m.w = ((b0.w + b1.w) + (b2.w + b3.w)) * inv;
        float4* mp = (float4*)(partials +
            ((((size_t)b * 2 + set) * SS + s) * HH + h) * DD);
        mp[d4] = m;  // zeros when invalid
    }
    if (tid == 0 && h == 0) validf[(b * 2 + set) * SS + s] = v;
}

// ---------------- Kernel 2: per-batch loss + final mean ----------------
// 1024 threads (16 waves) per batch-block: center pass split 4-way across
// thread quarters, cosine loop 2 segments/wave. Parametrized over HH.
__global__ __launch_bounds__(1024) void loss_kernel(
        const float* __restrict__ partials,  // [2*SS][HH][DD] per batch
        const int* __restrict__ validf,
        float* __restrict__ out) {
    __shared__ float cpart[4][DD];
    __shared__ float cs[DD];
    __shared__ float wred[4];
    __shared__ float wl1[16], wl2[16];

    int b = blockIdx.x;   // b%8 == blockIdx%8 -> same XCD that wrote partials
    int tid = threadIdx.x;
    int lane = tid & 63;
    int wave = tid >> 6;          // 0..15

    const float* pp = partials + (size_t)b * 2 * SS * HH * DD;
    const int* pv = validf + b * 2 * SS;  // 32 ints: pos[0..15], neg[16..31]

    int pcnt = 0, ncnt = 0;
#pragma unroll
    for (int s = 0; s < SS; ++s) { pcnt += (pv[s] != 0); ncnt += (pv[SS + s] != 0); }
    float pc = (float)pcnt;

    // center partial: thread (d, qq) sums pos segs [qq*4, qq*4+4) over all h
    int d  = tid & 255;
    int qq = tid >> 8;            // 0..3
    float cp = 0.f;
#pragma unroll
    for (int s = 0; s < 4; ++s) {
#pragma unroll
        for (int h = 0; h < HH; ++h)
            cp += pp[((qq * 4 + s) * HH + h) * DD + d];
    }
    cpart[qq][d] = cp;
    __syncthreads();

    // combine quarters -> center; invalid means are zero, matching ref
    float c = 0.f;
    if (tid < DD) {
        c = ((cpart[0][tid] + cpart[1][tid]) + (cpart[2][tid] + cpart[3][tid])) / pc;
        cs[tid] = c;
    }
    float cc = c * c;             // threads >= 256 contribute 0
#pragma unroll
    for (int off = 32; off > 0; off >>= 1) cc += __shfl_down(cc, off, 64);
    if (lane == 0 && wave < 4) wred[wave] = cc;
    __syncthreads();  // covers cs[] writes too
    float ncen = fmaxf(sqrtf((wred[0] + wred[1]) + (wred[2] + wred[3])), CEPS);

    // cosine terms: wave w handles segments w (pos) and w+16 (neg)
    float l1 = 0.f, l2 = 0.f;
#pragma unroll
    for (int gi = 0; gi < 2; ++gi) {
        int g = wave + 16 * gi;
        const float* mg = pp + (size_t)g * HH * DD;
        float dot = 0.f, nn = 0.f;
#pragma unroll
        for (int k = 0; k < 4; ++k) {
            int dk = lane + 64 * k;
            float a = 0.f;
#pragma unroll
            for (int h = 0; h < HH; ++h) a += mg[h * DD + dk];
            dot += a * cs[dk];
            nn  += a * a;
        }
#pragma unroll
        for (int off = 32; off > 0; off >>= 1) {
            dot += __shfl_down(dot, off, 64);
            nn  += __shfl_down(nn, off, 64);
        }
        if (lane == 0) {
            float na = fmaxf(sqrtf(nn), CEPS);
            float cosv = dot / (na * ncen);
            if (g < SS) { if (pv[g]) l1 += 1.0f - cosv; }
            else        { if (pv[g]) l2 += expf(cosv - 1.0f); }
        }
    }
    if (lane == 0) { wl1[wave] = l1; wl2[wave] = l2; }
    __syncthreads();
    if (tid == 0) {
        float L1 = 0.f, L2 = 0.f;
#pragma unroll
        for (int w = 0; w < 16; ++w) { L1 += wl1[w]; L2 += wl2[w]; }
        float val = L1 / pc + L2 / (float)ncnt;
        atomicAdd(out, val * (1.0f / (float)BB));
    }
}

extern "C" void kernel_launch(void* const* d_in, const int* in_sizes, int n_in,
                              void* d_out, int out_size, void* d_ws, size_t ws_size,
                              hipStream_t stream) {
    const float* feat = (const float*)d_in[0];
    const int* ipos   = (const int*)d_in[1];
    const int* ineg   = (const int*)d_in[2];
    float* out = (float*)d_out;

    char* ws = (char*)d_ws;
    size_t part_bytes = (size_t)BB * 2 * SS * HH * DD * sizeof(float);  // 4 MiB
    float* partials = (float*)ws;
    int*   validf   = (int*)(ws + part_bytes);

    seg_mean_kernel<<<BB * 2 * SS * HH, 256, 0, stream>>>(feat, ipos, ineg,
                                                          partials, validf, out);
    loss_kernel<<<BB, 1024, 0, stream>>>(partials, validf, out);
}

// Round 4
// 191.293 us; speedup vs baseline: 1.0158x; 1.0158x over previous
//
#include <hip/hip_runtime.h>
#include <math.h>

#define BB 64
#define TT 2048
#define DD 256
#define SS 16
#define HH 4          // blocks per segment. R3 post-mortem: HH=2 regressed
                      // (+1.1us) — straggler balance beats partials traffic.
                      // HH=4 (54-row max straggler) is the measured optimum.
#define CEPS 1e-8f

// ---------------- Kernel 1: per-segment partial means ----------------
// grid = BB*2*SS*HH = 8192 blocks, 256 threads. Each block sums a contiguous
// quarter of its segment's rows, pre-scaled by 1/seg_len, into partials.
// XCD swizzle: low 3 bits of blockIdx = b%8, so all 128 blocks of one batch
// land on one XCD consecutively -> pos/neg overlapping rows hit that XCD's L2.
// NOTE (R1 post-mortem): do NOT fuse the loss in via a completion gate —
// agent-scope fences flush the per-XCD L2 once per block and cost ~1 ms.
// A second dispatch costs ~2 us.
__global__ __launch_bounds__(256) void seg_mean_kernel(
        const float* __restrict__ feat,
        const int* __restrict__ idx_pos,
        const int* __restrict__ idx_neg,
        float* __restrict__ partials,  // [BB][2][SS][HH][DD]
        int* __restrict__ validf,      // [BB][2][SS]
        float* __restrict__ out) {
    // Zero the output here instead of a separate memset dispatch (R3 keep).
    // Visibility to the later loss_kernel dispatch is guaranteed by in-stream
    // kernel ordering.
    if (blockIdx.x == 0 && threadIdx.x == 0) out[0] = 0.f;

    int blk   = blockIdx.x;
    int xcd   = blk & 7;
    int inner = blk >> 3;          // 0..1023
    int work  = inner & 127;       // (set,s,h)
    int bg    = inner >> 7;        // 0..7
    int b     = bg * 8 + xcd;
    int set   = work >> 6;
    int s     = (work >> 2) & 15;
    int h     = work & 3;
    const int* row = (set == 0 ? idx_pos : idx_neg) + b * 32;

    // valid = cumprod(starts >= 0) up to and including s
    int v = 1;
    for (int j = 0; j <= s; ++j) v &= (row[2 * j] >= 0) ? 1 : 0;

    int start = row[2 * s];
    int end   = row[2 * s + 1];
    int seg_len = end - start;
    if (seg_len < 1) seg_len = 1;
    int t0 = start < 0 ? 0 : start;
    int t1 = start + seg_len;
    if (t1 > TT) t1 = TT;
    int len = t1 - t0;
    if (len < 0) len = 0;

    // this block's quarter of the row range
    int q0 = t0 + ((len * h) >> 2);
    int q1 = t0 + ((len * (h + 1)) >> 2);

    int tid = threadIdx.x;
    int d4  = tid & 63;
    int r   = tid >> 6;

    float4 a0 = make_float4(0.f, 0.f, 0.f, 0.f);
    float4 a1 = a0, a2 = a0, a3 = a0;
    if (v) {
        const float4* fp = (const float4*)(feat + (size_t)b * TT * DD);
        int t = q0 + r;
        for (; t + 12 < q1; t += 16) {
            float4 x0 = fp[(size_t)t * 64 + d4];
            float4 x1 = fp[(size_t)(t + 4) * 64 + d4];
            float4 x2 = fp[(size_t)(t + 8) * 64 + d4];
            float4 x3 = fp[(size_t)(t + 12) * 64 + d4];
            a0.x += x0.x; a0.y += x0.y; a0.z += x0.z; a0.w += x0.w;
            a1.x += x1.x; a1.y += x1.y; a1.z += x1.z; a1.w += x1.w;
            a2.x += x2.x; a2.y += x2.y; a2.z += x2.z; a2.w += x2.w;
            a3.x += x3.x; a3.y += x3.y; a3.z += x3.z; a3.w += x3.w;
        }
        for (; t < q1; t += 4) {
            float4 x = fp[(size_t)t * 64 + d4];
            a0.x += x.x; a0.y += x.y; a0.z += x.z; a0.w += x.w;
        }
    }
    float4 acc;
    acc.x = (a0.x + a1.x) + (a2.x + a3.x);
    acc.y = (a0.y + a1.y) + (a2.y + a3.y);
    acc.z = (a0.z + a1.z) + (a2.z + a3.z);
    acc.w = (a0.w + a1.w) + (a2.w + a3.w);

    __shared__ float4 red[256];
    red[tid] = acc;
    __syncthreads();
    if (r == 0) {
        float4 b0 = red[d4];
        float4 b1 = red[d4 + 64];
        float4 b2 = red[d4 + 128];
        float4 b3 = red[d4 + 192];
        float inv = 1.0f / (float)seg_len;
        float4 m;
        m.x = ((b0.x + b1.x) + (b2.x + b3.x)) * inv;
        m.y = ((b0.y + b1.y) + (b2.y + b3.y)) * inv;
        m.z = ((b0.z + b1.z) + (b2.z + b3.z)) * inv;
        m.w = ((b0.w + b1.w) + (b2.w + b3.w)) * inv;
        float4* mp = (float4*)(partials +
            ((((size_t)b * 2 + set) * SS + s) * HH + h) * DD);
        mp[d4] = m;  // zeros when invalid
    }
    if (tid == 0 && h == 0) validf[(b * 2 + set) * SS + s] = v;
}

// ---------------- Kernel 2: per-batch loss + final mean ----------------
// 1024 threads (16 waves) per batch-block: center pass split 4-way across
// thread quarters, cosine loop 2 segments/wave. Parametrized over HH.
__global__ __launch_bounds__(1024) void loss_kernel(
        const float* __restrict__ partials,  // [2*SS][HH][DD] per batch
        const int* __restrict__ validf,
        float* __restrict__ out) {
    __shared__ float cpart[4][DD];
    __shared__ float cs[DD];
    __shared__ float wred[4];
    __shared__ float wl1[16], wl2[16];

    int b = blockIdx.x;   // b%8 == blockIdx%8 -> same XCD that wrote partials
    int tid = threadIdx.x;
    int lane = tid & 63;
    int wave = tid >> 6;          // 0..15

    const float* pp = partials + (size_t)b * 2 * SS * HH * DD;
    const int* pv = validf + b * 2 * SS;  // 32 ints: pos[0..15], neg[16..31]

    int pcnt = 0, ncnt = 0;
#pragma unroll
    for (int s = 0; s < SS; ++s) { pcnt += (pv[s] != 0); ncnt += (pv[SS + s] != 0); }
    float pc = (float)pcnt;

    // center partial: thread (d, qq) sums pos segs [qq*4, qq*4+4) over all h
    int d  = tid & 255;
    int qq = tid >> 8;            // 0..3
    float cp = 0.f;
#pragma unroll
    for (int s = 0; s < 4; ++s) {
#pragma unroll
        for (int h = 0; h < HH; ++h)
            cp += pp[((qq * 4 + s) * HH + h) * DD + d];
    }
    cpart[qq][d] = cp;
    __syncthreads();

    // combine quarters -> center; invalid means are zero, matching ref
    float c = 0.f;
    if (tid < DD) {
        c = ((cpart[0][tid] + cpart[1][tid]) + (cpart[2][tid] + cpart[3][tid])) / pc;
        cs[tid] = c;
    }
    float cc = c * c;             // threads >= 256 contribute 0
#pragma unroll
    for (int off = 32; off > 0; off >>= 1) cc += __shfl_down(cc, off, 64);
    if (lane == 0 && wave < 4) wred[wave] = cc;
    __syncthreads();  // covers cs[] writes too
    float ncen = fmaxf(sqrtf((wred[0] + wred[1]) + (wred[2] + wred[3])), CEPS);

    // cosine terms: wave w handles segments w (pos) and w+16 (neg)
    float l1 = 0.f, l2 = 0.f;
#pragma unroll
    for (int gi = 0; gi < 2; ++gi) {
        int g = wave + 16 * gi;
        const float* mg = pp + (size_t)g * HH * DD;
        float dot = 0.f, nn = 0.f;
#pragma unroll
        for (int k = 0; k < 4; ++k) {
            int dk = lane + 64 * k;
            float a = 0.f;
#pragma unroll
            for (int h = 0; h < HH; ++h) a += mg[h * DD + dk];
            dot += a * cs[dk];
            nn  += a * a;
        }
#pragma unroll
        for (int off = 32; off > 0; off >>= 1) {
            dot += __shfl_down(dot, off, 64);
            nn  += __shfl_down(nn, off, 64);
        }
        if (lane == 0) {
            float na = fmaxf(sqrtf(nn), CEPS);
            float cosv = dot / (na * ncen);
            if (g < SS) { if (pv[g]) l1 += 1.0f - cosv; }
            else        { if (pv[g]) l2 += expf(cosv - 1.0f); }
        }
    }
    if (lane == 0) { wl1[wave] = l1; wl2[wave] = l2; }
    __syncthreads();
    if (tid == 0) {
        float L1 = 0.f, L2 = 0.f;
#pragma unroll
        for (int w = 0; w < 16; ++w) { L1 += wl1[w]; L2 += wl2[w]; }
        float val = L1 / pc + L2 / (float)ncnt;
        atomicAdd(out, val * (1.0f / (float)BB));
    }
}

extern "C" void kernel_launch(void* const* d_in, const int* in_sizes, int n_in,
                              void* d_out, int out_size, void* d_ws, size_t ws_size,
                              hipStream_t stream) {
    const float* feat = (const float*)d_in[0];
    const int* ipos   = (const int*)d_in[1];
    const int* ineg   = (const int*)d_in[2];
    float* out = (float*)d_out;

    char* ws = (char*)d_ws;
    size_t part_bytes = (size_t)BB * 2 * SS * HH * DD * sizeof(float);  // 8 MiB
    float* partials = (float*)ws;
    int*   validf   = (int*)(ws + part_bytes);

    seg_mean_kernel<<<BB * 2 * SS * HH, 256, 0, stream>>>(feat, ipos, ineg,
                                                          partials, validf, out);
    loss_kernel<<<BB, 1024, 0, stream>>>(partials, validf, out);
}